// Round 1
// baseline (1043.507 us; speedup 1.0000x reference)
//
#include <hip/hip_runtime.h>
#include <math.h>

#define BB 4
#define CC 256
#define NN 4096
#define DQ 32
#define TQ 32
#define TJ 32

// ---------------- Projection kernel ----------------
// P[b,o,n] = bias[o] + sum_c W[o,c]*x[b,c,n]
// o in [0,32): Wq -> Qws[b,o,n]; [32,64): Wk -> Kws; [64,320): Wv -> Vws
// All outputs laid out [B, rows, N] (Q stored transposed vs reference; attn
// kernel loads it coalesced along n).
__global__ __launch_bounds__(256) void proj_kernel(
    const float* __restrict__ x,
    const float* __restrict__ Wq, const float* __restrict__ bq,
    const float* __restrict__ Wk, const float* __restrict__ bk,
    const float* __restrict__ Wv, const float* __restrict__ bv,
    float* __restrict__ Qws, float* __restrict__ Kws, float* __restrict__ Vws)
{
    __shared__ float xs[CC][32];
    const int n0 = blockIdx.x * 32;
    const int b = blockIdx.y;
    const int tid = threadIdx.x;

    const float* xb = x + (size_t)b * CC * NN + n0;
    for (int idx = tid; idx < CC * 32; idx += 256) {
        int c = idx >> 5, n = idx & 31;
        xs[c][n] = xb[(size_t)c * NN + n];   // coalesced over n
    }
    __syncthreads();

    const int n = tid & 31;
    const int og = tid >> 5;           // 0..7, each handles 40 output rows
    for (int r = 0; r < 40; ++r) {
        int o = og * 40 + r;
        const float* wrow; float bias; float* dst;
        if (o < DQ) {
            wrow = Wq + o * CC; bias = bq[o];
            dst = Qws + ((size_t)b * DQ + o) * NN + n0 + n;
        } else if (o < 2 * DQ) {
            int o2 = o - DQ;
            wrow = Wk + o2 * CC; bias = bk[o2];
            dst = Kws + ((size_t)b * DQ + o2) * NN + n0 + n;
        } else {
            int o2 = o - 2 * DQ;
            wrow = Wv + o2 * CC; bias = bv[o2];
            dst = Vws + ((size_t)b * CC + o2) * NN + n0 + n;
        }
        float acc = bias;
        const float4* w4 = (const float4*)wrow;
        #pragma unroll 8
        for (int c4 = 0; c4 < CC / 4; ++c4) {
            float4 w = w4[c4];
            int c = c4 * 4;
            acc = fmaf(w.x, xs[c + 0][n],
                  fmaf(w.y, xs[c + 1][n],
                  fmaf(w.z, xs[c + 2][n],
                  fmaf(w.w, xs[c + 3][n], acc))));
        }
        *dst = acc;   // coalesced over n
    }
}

__device__ inline void fma4(float4& a, float p, const float4& v) {
    a.x = fmaf(p, v.x, a.x);
    a.y = fmaf(p, v.y, a.y);
    a.z = fmaf(p, v.z, a.z);
    a.w = fmaf(p, v.w, a.w);
}

// ---------------- Flash attention kernel (fp32) ----------------
// Per block: 32 queries of one batch. Online softmax over 128 key tiles of 32.
// Thread t: ig=t>>5 owns queries 4*ig..4*ig+3 ; cg=t&31 owns channels
// {4cg..4cg+3, 128+4cg..128+4cg+3}. acc = 4x2 float4 = 32 regs.
__global__ __launch_bounds__(256) void attn_kernel(
    const float* __restrict__ x,
    const float* __restrict__ Qws, const float* __restrict__ Kws,
    const float* __restrict__ Vws, float* __restrict__ out)
{
    __shared__ float qs[TQ][36];    // [i][d], stride 36 keeps float4 rows aligned
    __shared__ float ks[DQ][33];    // [d][j]
    __shared__ float ps[TJ][36];    // [j][i]
    __shared__ float vs[TJ][260];   // [j][c]; reused as os[i][c] in epilogue

    const int i0 = blockIdx.x * TQ;
    const int b = blockIdx.y;
    const int tid = threadIdx.x;
    const int cg = tid & 31;
    const int ig = tid >> 5;
    const int ib = ig * 4;

    // Q tile: qs[i][d] = Qws[b,d,i0+i]  (coalesced over i)
    {
        const float* Qb = Qws + (size_t)b * DQ * NN + i0;
        for (int idx = tid; idx < TQ * DQ; idx += 256) {
            int i = idx & 31, d = idx >> 5;
            qs[i][d] = Qb[(size_t)d * NN + i];
        }
    }

    float4 acc[4][2];
    float m_i[4], l_i[4];
    #pragma unroll
    for (int r = 0; r < 4; ++r) {
        acc[r][0] = make_float4(0.f, 0.f, 0.f, 0.f);
        acc[r][1] = make_float4(0.f, 0.f, 0.f, 0.f);
        m_i[r] = -__builtin_inff();
        l_i[r] = 0.f;
    }
    __syncthreads();

    const float* Kb = Kws + (size_t)b * DQ * NN;
    const float* Vb = Vws + (size_t)b * CC * NN;

    for (int j0 = 0; j0 < NN; j0 += TJ) {
        // stage K tile: ks[d][j] (coalesced over j)
        for (int idx = tid; idx < DQ * TJ; idx += 256) {
            int j = idx & 31, d = idx >> 5;
            ks[d][j] = Kb[(size_t)d * NN + j0 + j];
        }
        // stage V tile: vs[j][c] (coalesced over j)
        for (int idx = tid; idx < CC * TJ; idx += 256) {
            int j = idx & 31, c = idx >> 5;
            vs[j][c] = Vb[(size_t)c * NN + j0 + j];
        }
        __syncthreads();

        // S[i][cg] for i = ib..ib+3
        float s[4] = {0.f, 0.f, 0.f, 0.f};
        #pragma unroll
        for (int d4 = 0; d4 < DQ / 4; ++d4) {
            float k0 = ks[d4 * 4 + 0][cg];
            float k1 = ks[d4 * 4 + 1][cg];
            float k2 = ks[d4 * 4 + 2][cg];
            float k3 = ks[d4 * 4 + 3][cg];
            #pragma unroll
            for (int r = 0; r < 4; ++r) {
                float4 q = *(const float4*)&qs[ib + r][d4 * 4];
                s[r] = fmaf(q.x, k0, fmaf(q.y, k1, fmaf(q.z, k2, fmaf(q.w, k3, s[r]))));
            }
        }

        // online softmax over the 32 lanes of this ig-group
        float rmax[4], rsum[4];
        #pragma unroll
        for (int r = 0; r < 4; ++r) rmax[r] = s[r];
        #pragma unroll
        for (int off = 16; off > 0; off >>= 1) {
            #pragma unroll
            for (int r = 0; r < 4; ++r)
                rmax[r] = fmaxf(rmax[r], __shfl_xor(rmax[r], off, 32));
        }
        float alpha[4];
        #pragma unroll
        for (int r = 0; r < 4; ++r) {
            float mnew = fmaxf(m_i[r], rmax[r]);
            alpha[r] = __expf(m_i[r] - mnew);
            m_i[r] = mnew;
            s[r] = __expf(s[r] - mnew);
            rsum[r] = s[r];
        }
        #pragma unroll
        for (int off = 16; off > 0; off >>= 1) {
            #pragma unroll
            for (int r = 0; r < 4; ++r)
                rsum[r] += __shfl_xor(rsum[r], off, 32);
        }
        #pragma unroll
        for (int r = 0; r < 4; ++r) {
            l_i[r] = l_i[r] * alpha[r] + rsum[r];
            acc[r][0].x *= alpha[r]; acc[r][0].y *= alpha[r];
            acc[r][0].z *= alpha[r]; acc[r][0].w *= alpha[r];
            acc[r][1].x *= alpha[r]; acc[r][1].y *= alpha[r];
            acc[r][1].z *= alpha[r]; acc[r][1].w *= alpha[r];
            ps[cg][ib + r] = s[r];
        }
        __syncthreads();

        // PV: acc[r] += P[i][j] * V[c][j]
        #pragma unroll 4
        for (int j = 0; j < TJ; ++j) {
            float4 p4 = *(const float4*)&ps[j][ib];
            float4 v0 = *(const float4*)&vs[j][cg * 4];
            float4 v1 = *(const float4*)&vs[j][128 + cg * 4];
            fma4(acc[0][0], p4.x, v0); fma4(acc[0][1], p4.x, v1);
            fma4(acc[1][0], p4.y, v0); fma4(acc[1][1], p4.y, v1);
            fma4(acc[2][0], p4.z, v0); fma4(acc[2][1], p4.z, v1);
            fma4(acc[3][0], p4.w, v0); fma4(acc[3][1], p4.w, v1);
        }
        __syncthreads();  // protect ks/vs/ps for next iteration
    }

    // epilogue: normalize, transpose through LDS (reuse vs as os[i][c]),
    // fused residual add, coalesced store
    #pragma unroll
    for (int r = 0; r < 4; ++r) {
        float inv = 1.0f / l_i[r];
        acc[r][0].x *= inv; acc[r][0].y *= inv; acc[r][0].z *= inv; acc[r][0].w *= inv;
        acc[r][1].x *= inv; acc[r][1].y *= inv; acc[r][1].z *= inv; acc[r][1].w *= inv;
        *(float4*)&vs[ib + r][cg * 4] = acc[r][0];
        *(float4*)&vs[ib + r][128 + cg * 4] = acc[r][1];
    }
    __syncthreads();

    const float* xb = x + (size_t)b * CC * NN + i0;
    float* ob = out + (size_t)b * CC * NN + i0;
    for (int s2 = 0; s2 < 32; ++s2) {
        int c = (tid >> 5) + s2 * 8;
        int i = tid & 31;
        ob[(size_t)c * NN + i] = xb[(size_t)c * NN + i] + vs[i][c];
    }
}

extern "C" void kernel_launch(void* const* d_in, const int* in_sizes, int n_in,
                              void* d_out, int out_size, void* d_ws, size_t ws_size,
                              hipStream_t stream) {
    const float* x  = (const float*)d_in[0];
    const float* Wq = (const float*)d_in[1];
    const float* bq = (const float*)d_in[2];
    const float* Wk = (const float*)d_in[3];
    const float* bk = (const float*)d_in[4];
    const float* Wv = (const float*)d_in[5];
    const float* bv = (const float*)d_in[6];
    float* out = (float*)d_out;

    // workspace: Q [B,DQ,N] | K [B,DQ,N] | V [B,C,N]  = 20 MB total
    float* Qws = (float*)d_ws;
    float* Kws = Qws + (size_t)BB * DQ * NN;
    float* Vws = Kws + (size_t)BB * DQ * NN;

    proj_kernel<<<dim3(NN / 32, BB), 256, 0, stream>>>(
        x, Wq, bq, Wk, bk, Wv, bv, Qws, Kws, Vws);
    attn_kernel<<<dim3(NN / TQ, BB), 256, 0, stream>>>(
        x, Qws, Kws, Vws, out);
}

// Round 2
// 372.045 us; speedup vs baseline: 2.8048x; 2.8048x over previous
//
#include <hip/hip_runtime.h>
#include <math.h>

#define BB 4
#define CC 256
#define NN 4096
#define DQ 32

typedef _Float16 half8 __attribute__((ext_vector_type(8)));
typedef _Float16 half4 __attribute__((ext_vector_type(4)));
typedef float float4v __attribute__((ext_vector_type(4)));

// ---------------- Projection kernel ----------------
// Computes Q,K,V (1x1 convs) in fp32, stores f16.
// Qt/Kt: [B][N][32]  (n-major so attn reads Q fragments coalesced from global)
// Vh:    [B][C][N]   (natural layout)
__global__ __launch_bounds__(256) void proj_kernel(
    const float* __restrict__ x,
    const float* __restrict__ Wq, const float* __restrict__ bq,
    const float* __restrict__ Wk, const float* __restrict__ bk,
    const float* __restrict__ Wv, const float* __restrict__ bv,
    _Float16* __restrict__ Qt, _Float16* __restrict__ Kt,
    _Float16* __restrict__ Vh)
{
    __shared__ float xs[CC][32];
    const int n0 = blockIdx.x * 32;
    const int b = blockIdx.y;
    const int tid = threadIdx.x;

    const float* xb = x + (size_t)b * CC * NN + n0;
    for (int idx = tid; idx < CC * 32; idx += 256) {
        int c = idx >> 5, n = idx & 31;
        xs[c][n] = xb[(size_t)c * NN + n];
    }
    __syncthreads();

    _Float16* Qtb = Qt + (size_t)b * NN * DQ;
    _Float16* Ktb = Kt + (size_t)b * NN * DQ;
    _Float16* Vb  = Vh + (size_t)b * CC * NN;

    const int n = tid & 31;
    const int og = tid >> 5;
    for (int r = 0; r < 40; ++r) {
        int o = og * 40 + r;
        const float* wrow; float bias; _Float16* dst;
        if (o < DQ) {
            wrow = Wq + o * CC; bias = bq[o];
            dst = Qtb + (size_t)(n0 + n) * DQ + o;
        } else if (o < 2 * DQ) {
            int o2 = o - DQ;
            wrow = Wk + o2 * CC; bias = bk[o2];
            dst = Ktb + (size_t)(n0 + n) * DQ + o2;
        } else {
            int o2 = o - 2 * DQ;
            wrow = Wv + o2 * CC; bias = bv[o2];
            dst = Vb + (size_t)o2 * NN + n0 + n;
        }
        float acc = bias;
        const float4* w4 = (const float4*)wrow;
        #pragma unroll 8
        for (int c4 = 0; c4 < CC / 4; ++c4) {
            float4 w = w4[c4];
            int c = c4 * 4;
            acc = fmaf(w.x, xs[c + 0][n],
                  fmaf(w.y, xs[c + 1][n],
                  fmaf(w.z, xs[c + 2][n],
                  fmaf(w.w, xs[c + 3][n], acc))));
        }
        *dst = (_Float16)acc;
    }
}

// ---------------- MFMA flash attention (f16 in, fp32 accum) ----------------
// Block: 256 thr = 4 waves, 32 queries (i0..i0+31) of one batch.
// Transposed formulation: S^T = K·Q^T and O^T = V·P^T so the MFMA C-layout
// column (lane&15) is the query index -> softmax state is per-lane scalar.
// Wave w owns output channels [64w, 64w+64).
// j-loop: 64 keys per tile; K tile + V tile staged in XOR-swizzled LDS.
__global__ __launch_bounds__(256) void attn_kernel(
    const float* __restrict__ x,
    const _Float16* __restrict__ Qt, const _Float16* __restrict__ Kt,
    const _Float16* __restrict__ Vh, float* __restrict__ out)
{
    __shared__ _Float16 k_lds[64 * 32];       // [j][d], d in 4 groups of 8, grp ^= (j&3)
    __shared__ _Float16 v_lds[256 * 64];      // [c][j], j in 8 groups of 8, grp ^= (c&7)
    __shared__ _Float16 ps[4][32 * 72];       // per-wave P: [i][j], row stride 72 (pad)

    const int tid = threadIdx.x;
    const int w = tid >> 6;
    const int lane = tid & 63;
    const int i16 = lane & 15;
    const int q = lane >> 4;
    const int i0 = blockIdx.x * 32;
    const int b = blockIdx.y;

    const _Float16* Ktb = Kt + (size_t)b * NN * DQ;
    const _Float16* Vb  = Vh + (size_t)b * CC * NN;

    // Q B-fragments (persistent): B[k=d=q*8+jj][n=i]
    half8 qb[2];
    {
        const _Float16* Qtb = Qt + (size_t)b * NN * DQ;
        qb[0] = *(const half8*)(Qtb + (size_t)(i0 + i16) * DQ + q * 8);
        qb[1] = *(const half8*)(Qtb + (size_t)(i0 + 16 + i16) * DQ + q * 8);
    }

    float4v O[4][2];
    #pragma unroll
    for (int ct = 0; ct < 4; ++ct)
        #pragma unroll
        for (int it = 0; it < 2; ++it)
            O[ct][it] = (float4v){0.f, 0.f, 0.f, 0.f};
    float m_i[2] = {-INFINITY, -INFINITY};
    float l_i[2] = {0.f, 0.f};

    _Float16* myps = &ps[w][0];

    for (int j0 = 0; j0 < NN; j0 += 64) {
        __syncthreads();   // previous iteration's LDS reads done
        // ---- stage K tile: k_lds[j][d] with d-group swizzle ----
        {
            int j = tid >> 2, dg = tid & 3;
            half8 kv = *(const half8*)(Ktb + (size_t)(j0 + j) * DQ + dg * 8);
            *(half8*)&k_lds[j * 32 + ((dg ^ (j & 3)) * 8)] = kv;
        }
        // ---- stage V tile: v_lds[c][j] with j-group swizzle ----
        {
            int cb = tid >> 3, jg = tid & 7;
            #pragma unroll
            for (int u = 0; u < 8; ++u) {
                int c = u * 32 + cb;
                half8 vv = *(const half8*)(Vb + (size_t)c * NN + j0 + jg * 8);
                *(half8*)&v_lds[c * 64 + ((jg ^ (c & 7)) * 8)] = vv;
            }
        }
        __syncthreads();

        // ---- S^T = K·Q^T : tiles (jt 0..3) x (it 0..1) ----
        half8 ka[4];
        #pragma unroll
        for (int jt = 0; jt < 4; ++jt) {
            int j = jt * 16 + i16;
            ka[jt] = *(const half8*)&k_lds[j * 32 + ((q ^ (j & 3)) * 8)];
        }
        float4v s[4][2];
        #pragma unroll
        for (int jt = 0; jt < 4; ++jt)
            #pragma unroll
            for (int it = 0; it < 2; ++it) {
                float4v z = {0.f, 0.f, 0.f, 0.f};
                s[jt][it] = __builtin_amdgcn_mfma_f32_16x16x32_f16(ka[jt], qb[it], z, 0, 0, 0);
            }

        // ---- online softmax (per lane: query i = 16*it + i16) ----
        float alpha[2];
        #pragma unroll
        for (int it = 0; it < 2; ++it) {
            float mx = -INFINITY;
            #pragma unroll
            for (int jt = 0; jt < 4; ++jt)
                #pragma unroll
                for (int r = 0; r < 4; ++r)
                    mx = fmaxf(mx, s[jt][it][r]);
            mx = fmaxf(mx, __shfl_xor(mx, 16, 64));
            mx = fmaxf(mx, __shfl_xor(mx, 32, 64));
            float mnew = fmaxf(m_i[it], mx);
            alpha[it] = __expf(m_i[it] - mnew);
            m_i[it] = mnew;
            float sum = 0.f;
            #pragma unroll
            for (int jt = 0; jt < 4; ++jt)
                #pragma unroll
                for (int r = 0; r < 4; ++r) {
                    float p = __expf(s[jt][it][r] - mnew);
                    s[jt][it][r] = p;
                    sum += p;
                }
            sum += __shfl_xor(sum, 16, 64);
            sum += __shfl_xor(sum, 32, 64);
            l_i[it] = l_i[it] * alpha[it] + sum;
        }

        // ---- rescale O, write P (f16) to wave-private LDS ----
        #pragma unroll
        for (int ct = 0; ct < 4; ++ct)
            #pragma unroll
            for (int it = 0; it < 2; ++it) {
                O[ct][it][0] *= alpha[it]; O[ct][it][1] *= alpha[it];
                O[ct][it][2] *= alpha[it]; O[ct][it][3] *= alpha[it];
            }
        #pragma unroll
        for (int jt = 0; jt < 4; ++jt)
            #pragma unroll
            for (int it = 0; it < 2; ++it) {
                half4 hv = { (_Float16)s[jt][it][0], (_Float16)s[jt][it][1],
                             (_Float16)s[jt][it][2], (_Float16)s[jt][it][3] };
                *(half4*)&myps[(16 * it + i16) * 72 + 16 * jt + 4 * q] = hv;
            }

        // ---- O^T += V·P^T ----
        half8 pb[2][2];
        #pragma unroll
        for (int ks = 0; ks < 2; ++ks)
            #pragma unroll
            for (int it = 0; it < 2; ++it)
                pb[ks][it] = *(const half8*)&myps[(16 * it + i16) * 72 + 32 * ks + 8 * q];
        #pragma unroll
        for (int ct = 0; ct < 4; ++ct) {
            int c = 64 * w + 16 * ct + i16;
            #pragma unroll
            for (int ks = 0; ks < 2; ++ks) {
                int g = 4 * ks + q;
                half8 va = *(const half8*)&v_lds[c * 64 + ((g ^ (c & 7)) * 8)];
                #pragma unroll
                for (int it = 0; it < 2; ++it)
                    O[ct][it] = __builtin_amdgcn_mfma_f32_16x16x32_f16(va, pb[ks][it], O[ct][it], 0, 0, 0);
            }
        }
    }

    // ---- epilogue: O/l + residual, direct from C-layout (coalesced 64B segs) ----
    float inv[2] = {1.f / l_i[0], 1.f / l_i[1]};
    const float* xb = x + (size_t)b * CC * NN;
    float* ob = out + (size_t)b * CC * NN;
    #pragma unroll
    for (int ct = 0; ct < 4; ++ct)
        #pragma unroll
        for (int it = 0; it < 2; ++it)
            #pragma unroll
            for (int r = 0; r < 4; ++r) {
                int c = 64 * w + 16 * ct + 4 * q + r;
                size_t idx = (size_t)c * NN + i0 + 16 * it + i16;
                ob[idx] = xb[idx] + O[ct][it][r] * inv[it];
            }
}

extern "C" void kernel_launch(void* const* d_in, const int* in_sizes, int n_in,
                              void* d_out, int out_size, void* d_ws, size_t ws_size,
                              hipStream_t stream) {
    const float* x  = (const float*)d_in[0];
    const float* Wq = (const float*)d_in[1];
    const float* bq = (const float*)d_in[2];
    const float* Wk = (const float*)d_in[3];
    const float* bk = (const float*)d_in[4];
    const float* Wv = (const float*)d_in[5];
    const float* bv = (const float*)d_in[6];
    float* out = (float*)d_out;

    // workspace: Qt [B,N,32] f16 (1MB) | Kt [B,N,32] f16 (1MB) | Vh [B,C,N] f16 (8MB)
    _Float16* Qt = (_Float16*)d_ws;
    _Float16* Kt = Qt + (size_t)BB * NN * DQ;
    _Float16* Vh = Kt + (size_t)BB * NN * DQ;

    proj_kernel<<<dim3(NN / 32, BB), 256, 0, stream>>>(
        x, Wq, bq, Wk, bk, Wv, bv, Qt, Kt, Vh);
    attn_kernel<<<dim3(NN / 32, BB), 256, 0, stream>>>(
        x, Qt, Kt, Vh, out);
}

// Round 3
// 205.130 us; speedup vs baseline: 5.0870x; 1.8137x over previous
//
#include <hip/hip_runtime.h>
#include <math.h>

#define BB 4
#define CC 256
#define NN 4096
#define DQ 32
#define LOG2E 1.44269504f

typedef _Float16 half8 __attribute__((ext_vector_type(8)));
typedef _Float16 half4 __attribute__((ext_vector_type(4)));
typedef float float4v __attribute__((ext_vector_type(4)));

// ---------------- prep: W -> f16 (log2e folded into Wq/bq) ----------------
// Wh[320][256] f16: rows 0-31 Wq*log2e, 32-63 Wk, 64-319 Wv. bh[320] f32.
__global__ __launch_bounds__(64) void prep_kernel(
    const float* __restrict__ Wq, const float* __restrict__ bq,
    const float* __restrict__ Wk, const float* __restrict__ bk,
    const float* __restrict__ Wv, const float* __restrict__ bv,
    _Float16* __restrict__ Wh, float* __restrict__ bh)
{
    int o = blockIdx.x, t = threadIdx.x;
    const float* src; float scale = 1.0f, bias;
    if (o < DQ)            { src = Wq + o * CC;        scale = LOG2E; bias = bq[o] * LOG2E; }
    else if (o < 2 * DQ)   { src = Wk + (o - DQ) * CC;                bias = bk[o - DQ]; }
    else                   { src = Wv + (o - 2 * DQ) * CC;            bias = bv[o - 2 * DQ]; }
    float4 v = *(const float4*)(src + t * 4);
    half4 h = { (_Float16)(v.x * scale), (_Float16)(v.y * scale),
                (_Float16)(v.z * scale), (_Float16)(v.w * scale) };
    *(half4*)(Wh + o * CC + t * 4) = h;
    if (t == 0) bh[o] = bias;
}

// ---------------- proj: MFMA GEMM, all 320 outputs x 64-pixel tile ----------------
// D[o][n] = Wh[o][:] . x[:, n] + bh[o].  Qt/Kt: [b][n][32] f16 (n-major).
// Vh: [b][c][n] f16.  Wave w owns o-tiles [5w,5w+5).
__global__ __launch_bounds__(256) void proj_kernel(
    const float* __restrict__ x, const _Float16* __restrict__ Wh,
    const float* __restrict__ bh,
    _Float16* __restrict__ Qt, _Float16* __restrict__ Kt,
    _Float16* __restrict__ Vh)
{
    __shared__ _Float16 xl[64 * 256];     // [n][c], chunk-of-8 XOR swizzle: chunk' = (c>>3) ^ (n&31)
    __shared__ _Float16 os_qk[64 * 72];   // [n][o<64 + pad]
    __shared__ _Float16 os_v[256 * 72];   // [c][n + pad]

    const int tid = threadIdx.x;
    const int lane = tid & 63, w = tid >> 6;
    const int i16 = lane & 15, q = lane >> 4;
    const int n0 = blockIdx.x * 64, b = blockIdx.y;

    // stage x tile transposed to f16 [n][c] with swizzle
    const float* xb = x + (size_t)b * CC * NN + n0;
    #pragma unroll
    for (int u = 0; u < 16; ++u) {
        int idx = u * 256 + tid;
        int c = idx >> 4, n4 = idx & 15;
        float4 v = *(const float4*)(xb + (size_t)c * NN + n4 * 4);
        int chunk = c >> 3, cl = c & 7;
        float vv[4] = {v.x, v.y, v.z, v.w};
        #pragma unroll
        for (int e = 0; e < 4; ++e) {
            int n = n4 * 4 + e;
            xl[n * 256 + ((chunk ^ (n & 31)) * 8) + cl] = (_Float16)vv[e];
        }
    }

    // bias init (C-layout: reg r <-> row o offset r)
    float4v acc[5][4];
    const int obase = 80 * w;
    #pragma unroll
    for (int ot = 0; ot < 5; ++ot) {
        float4 b4 = *(const float4*)(bh + obase + 16 * ot + 4 * q);
        #pragma unroll
        for (int nt = 0; nt < 4; ++nt)
            acc[ot][nt] = (float4v){b4.x, b4.y, b4.z, b4.w};
    }
    __syncthreads();

    // K loop: 8 steps of 32 channels
    #pragma unroll
    for (int k = 0; k < 8; ++k) {
        half8 af[5], bf[4];
        #pragma unroll
        for (int ot = 0; ot < 5; ++ot)
            af[ot] = *(const half8*)(Wh + (size_t)(obase + 16 * ot + i16) * CC + k * 32 + 8 * q);
        #pragma unroll
        for (int nt = 0; nt < 4; ++nt) {
            int n = 16 * nt + i16;
            bf[nt] = *(const half8*)&xl[n * 256 + (((4 * k + q) ^ (n & 31)) * 8)];
        }
        #pragma unroll
        for (int ot = 0; ot < 5; ++ot)
            #pragma unroll
            for (int nt = 0; nt < 4; ++nt)
                acc[ot][nt] = __builtin_amdgcn_mfma_f32_16x16x32_f16(af[ot], bf[nt], acc[ot][nt], 0, 0, 0);
    }

    // epilogue: write D into transpose buffers
    #pragma unroll
    for (int ot = 0; ot < 5; ++ot) {
        int og = obase + 16 * ot;
        #pragma unroll
        for (int nt = 0; nt < 4; ++nt) {
            int n = 16 * nt + i16;
            if (og < 64) {   // Q/K rows: pack 4 consecutive o into b64
                half4 hv = { (_Float16)acc[ot][nt][0], (_Float16)acc[ot][nt][1],
                             (_Float16)acc[ot][nt][2], (_Float16)acc[ot][nt][3] };
                *(half4*)&os_qk[n * 72 + og + 4 * q] = hv;
            } else {         // V rows: scattered b16 into [c][n]
                int cb = og - 64 + 4 * q;
                #pragma unroll
                for (int r = 0; r < 4; ++r)
                    os_v[(cb + r) * 72 + n] = (_Float16)acc[ot][nt][r];
            }
        }
    }
    __syncthreads();

    // coalesced global stores
    _Float16* Qtb = Qt + (size_t)b * NN * DQ;
    _Float16* Ktb = Kt + (size_t)b * NN * DQ;
    #pragma unroll
    for (int u = 0; u < 2; ++u) {
        int ct = u * 256 + tid;
        int n = ct >> 3, p = ct & 7;
        half8 hv = *(const half8*)&os_qk[n * 72 + 8 * p];
        if (p < 4) *(half8*)(Qtb + (size_t)(n0 + n) * DQ + 8 * p) = hv;
        else       *(half8*)(Ktb + (size_t)(n0 + n) * DQ + 8 * (p - 4)) = hv;
    }
    _Float16* Vb = Vh + (size_t)b * CC * NN;
    #pragma unroll
    for (int u = 0; u < 8; ++u) {
        int c = u * 32 + (tid >> 3), p = tid & 7;
        half8 hv = *(const half8*)&os_v[c * 72 + 8 * p];
        *(half8*)(Vb + (size_t)c * NN + n0 + 8 * p) = hv;
    }
}

// ---------------- rowstat: exact per-query (m2, l) of S2 = K.Q^T ----------------
// Per block: 64 queries (16/wave), half of the key range. Per-lane online (m,l),
// cross-quad combine at the end. M2/L: [b][jhalf][N] f32.
__global__ __launch_bounds__(256) void rowstat_kernel(
    const _Float16* __restrict__ Qt, const _Float16* __restrict__ Kt,
    float* __restrict__ M2, float* __restrict__ L)
{
    __shared__ _Float16 k_lds[64 * 32];
    const int tid = threadIdx.x;
    const int lane = tid & 63, w = tid >> 6;
    const int i16 = lane & 15, q = lane >> 4;
    const int q0 = blockIdx.x * 64, js = blockIdx.y, b = blockIdx.z;

    const _Float16* Qtb = Qt + (size_t)b * NN * DQ;
    const _Float16* Ktb = Kt + (size_t)b * NN * DQ;
    half8 qb = *(const half8*)(Qtb + (size_t)(q0 + 16 * w + i16) * DQ + 8 * q);

    float m = -INFINITY, l = 0.f;
    for (int j0 = js * 2048; j0 < (js + 1) * 2048; j0 += 64) {
        __syncthreads();
        {
            int j = tid >> 2, dg = tid & 3;
            half8 kv = *(const half8*)(Ktb + (size_t)(j0 + j) * DQ + 8 * dg);
            *(half8*)&k_lds[j * 32 + ((dg ^ (j & 3)) * 8)] = kv;
        }
        __syncthreads();
        float4v s[4];
        #pragma unroll
        for (int jt = 0; jt < 4; ++jt) {
            int j = 16 * jt + i16;
            half8 ka = *(const half8*)&k_lds[j * 32 + ((q ^ (j & 3)) * 8)];
            float4v z = {0.f, 0.f, 0.f, 0.f};
            s[jt] = __builtin_amdgcn_mfma_f32_16x16x32_f16(ka, qb, z, 0, 0, 0);
        }
        float tmax = s[0][0];
        #pragma unroll
        for (int jt = 0; jt < 4; ++jt)
            #pragma unroll
            for (int r = 0; r < 4; ++r)
                tmax = fmaxf(tmax, s[jt][r]);
        float mnew = fmaxf(m, tmax);
        float sum = 0.f;
        #pragma unroll
        for (int jt = 0; jt < 4; ++jt)
            #pragma unroll
            for (int r = 0; r < 4; ++r)
                sum += exp2f(s[jt][r] - mnew);
        l = l * exp2f(m - mnew) + sum;
        m = mnew;
    }
    // combine the 4 quads (same query, different key rows)
    #pragma unroll
    for (int off = 16; off <= 32; off <<= 1) {
        float mo = __shfl_xor(m, off, 64);
        float lo = __shfl_xor(l, off, 64);
        float mn = fmaxf(m, mo);
        l = l * exp2f(m - mn) + lo * exp2f(mo - mn);
        m = mn;
    }
    if (q == 0) {
        int qi = q0 + 16 * w + i16;
        M2[((size_t)b * 2 + js) * NN + qi] = m;
        L[((size_t)b * 2 + js) * NN + qi] = l;
    }
}

// ---------------- attn: single-pass, precomputed (m2, 1/l) ----------------
// Wave w computes S^T strip jt=w only (no replication); shared P buffer; 3-barrier loop.
__global__ __launch_bounds__(256) void attn_kernel(
    const float* __restrict__ x,
    const _Float16* __restrict__ Qt, const _Float16* __restrict__ Kt,
    const _Float16* __restrict__ Vh,
    const float* __restrict__ M2, const float* __restrict__ L,
    float* __restrict__ out)
{
    __shared__ _Float16 k_lds[64 * 32];    // [j][d], d-chunk ^= (j&3)
    __shared__ _Float16 v_lds[256 * 64];   // [c][j], j-chunk ^= (c&7)
    __shared__ _Float16 ps[32 * 72];       // shared P: [i][j + pad]

    const int tid = threadIdx.x;
    const int w = tid >> 6, lane = tid & 63;
    const int i16 = lane & 15, q = lane >> 4;
    const int i0 = blockIdx.x * 32, b = blockIdx.y;

    const _Float16* Ktb = Kt + (size_t)b * NN * DQ;
    const _Float16* Vb  = Vh + (size_t)b * CC * NN;

    // combine the two j-halves of (m,l); per-lane for its 2 queries
    float m2v[2], linv[2];
    #pragma unroll
    for (int it = 0; it < 2; ++it) {
        int qi = i0 + 16 * it + i16;
        float m0 = M2[((size_t)b * 2 + 0) * NN + qi];
        float m1 = M2[((size_t)b * 2 + 1) * NN + qi];
        float l0 = L[((size_t)b * 2 + 0) * NN + qi];
        float l1 = L[((size_t)b * 2 + 1) * NN + qi];
        float mm = fmaxf(m0, m1);
        float ll = l0 * exp2f(m0 - mm) + l1 * exp2f(m1 - mm);
        m2v[it] = mm;
        linv[it] = 1.0f / ll;
    }

    half8 qb[2];
    {
        const _Float16* Qtb = Qt + (size_t)b * NN * DQ;
        qb[0] = *(const half8*)(Qtb + (size_t)(i0 + i16) * DQ + 8 * q);
        qb[1] = *(const half8*)(Qtb + (size_t)(i0 + 16 + i16) * DQ + 8 * q);
    }

    float4v O[4][2];
    #pragma unroll
    for (int ct = 0; ct < 4; ++ct)
        #pragma unroll
        for (int it = 0; it < 2; ++it)
            O[ct][it] = (float4v){0.f, 0.f, 0.f, 0.f};

    for (int j0 = 0; j0 < NN; j0 += 64) {
        __syncthreads();   // A: prior PV reads + prior ps done
        {
            int j = tid >> 2, dg = tid & 3;
            half8 kv = *(const half8*)(Ktb + (size_t)(j0 + j) * DQ + 8 * dg);
            *(half8*)&k_lds[j * 32 + ((dg ^ (j & 3)) * 8)] = kv;
        }
        {
            int cb = tid >> 3, jg = tid & 7;
            #pragma unroll
            for (int u = 0; u < 8; ++u) {
                int c = u * 32 + cb;
                half8 vv = *(const half8*)(Vb + (size_t)c * NN + j0 + jg * 8);
                *(half8*)&v_lds[c * 64 + ((jg ^ (c & 7)) * 8)] = vv;
            }
        }
        __syncthreads();   // B: tiles staged

        // S^T strip for this wave: keys [j0+16w, j0+16w+16)
        {
            int j = 16 * w + i16;
            half8 ka = *(const half8*)&k_lds[j * 32 + ((q ^ (j & 3)) * 8)];
            #pragma unroll
            for (int it = 0; it < 2; ++it) {
                float4v z = {0.f, 0.f, 0.f, 0.f};
                float4v s = __builtin_amdgcn_mfma_f32_16x16x32_f16(ka, qb[it], z, 0, 0, 0);
                half4 hv = { (_Float16)exp2f(s[0] - m2v[it]),
                             (_Float16)exp2f(s[1] - m2v[it]),
                             (_Float16)exp2f(s[2] - m2v[it]),
                             (_Float16)exp2f(s[3] - m2v[it]) };
                *(half4*)&ps[(16 * it + i16) * 72 + 16 * w + 4 * q] = hv;
            }
        }
        __syncthreads();   // C: P ready

        half8 pb[2][2];
        #pragma unroll
        for (int ks = 0; ks < 2; ++ks)
            #pragma unroll
            for (int it = 0; it < 2; ++it)
                pb[ks][it] = *(const half8*)&ps[(16 * it + i16) * 72 + 32 * ks + 8 * q];
        #pragma unroll
        for (int ct = 0; ct < 4; ++ct) {
            int c = 64 * w + 16 * ct + i16;
            #pragma unroll
            for (int ks = 0; ks < 2; ++ks) {
                int g = 4 * ks + q;
                half8 va = *(const half8*)&v_lds[c * 64 + ((g ^ (c & 7)) * 8)];
                #pragma unroll
                for (int it = 0; it < 2; ++it)
                    O[ct][it] = __builtin_amdgcn_mfma_f32_16x16x32_f16(va, pb[ks][it], O[ct][it], 0, 0, 0);
            }
        }
    }

    // epilogue: O * (1/l) + residual
    const float* xb = x + (size_t)b * CC * NN;
    float* ob = out + (size_t)b * CC * NN;
    #pragma unroll
    for (int ct = 0; ct < 4; ++ct)
        #pragma unroll
        for (int it = 0; it < 2; ++it)
            #pragma unroll
            for (int r = 0; r < 4; ++r) {
                int c = 64 * w + 16 * ct + 4 * q + r;
                size_t idx = (size_t)c * NN + i0 + 16 * it + i16;
                ob[idx] = xb[idx] + O[ct][it][r] * linv[it];
            }
}

extern "C" void kernel_launch(void* const* d_in, const int* in_sizes, int n_in,
                              void* d_out, int out_size, void* d_ws, size_t ws_size,
                              hipStream_t stream) {
    const float* x  = (const float*)d_in[0];
    const float* Wq = (const float*)d_in[1];
    const float* bq = (const float*)d_in[2];
    const float* Wk = (const float*)d_in[3];
    const float* bk = (const float*)d_in[4];
    const float* Wv = (const float*)d_in[5];
    const float* bv = (const float*)d_in[6];
    float* out = (float*)d_out;

    char* ws = (char*)d_ws;
    _Float16* Wh = (_Float16*)(ws);                 // 320*256*2 = 163840
    float*    bh = (float*)(ws + 163840);           // 1280
    _Float16* Qt = (_Float16*)(ws + 262144);        // 4*4096*32*2 = 1 MB
    _Float16* Kt = (_Float16*)(ws + 1310720);       // 1 MB
    _Float16* Vh = (_Float16*)(ws + 2359296);       // 4*256*4096*2 = 8 MB
    float*    M2 = (float*)(ws + 10747904);         // 4*2*4096*4 = 128 KB
    float*    L  = (float*)(ws + 10878976);         // 128 KB

    prep_kernel<<<dim3(320), 64, 0, stream>>>(Wq, bq, Wk, bk, Wv, bv, Wh, bh);
    proj_kernel<<<dim3(NN / 64, BB), 256, 0, stream>>>(x, Wh, bh, Qt, Kt, Vh);
    rowstat_kernel<<<dim3(NN / 64, 2, BB), 256, 0, stream>>>(Qt, Kt, M2, L);
    attn_kernel<<<dim3(NN / 32, BB), 256, 0, stream>>>(x, Qt, Kt, Vh, M2, L, out);
}